// Round 1
// baseline (648.810 us; speedup 1.0000x reference)
//
#include <hip/hip_runtime.h>

#define NFEAT 1024
#define NHEAD 16
#define DK 64
#define TCHUNK 1024

// ---------------------------------------------------------------------------
// GEMM: C[1024x1024] = A[1024x1024] @ B[1024x1024] + bias, f32 row-major.
// 64x64 output tile per block, BK=32, 256 threads, 4x4 accum per thread.
// A staged transposed ([k][m]) so the inner loop is two ds_read_b128 + 16 fma.
// ---------------------------------------------------------------------------
__device__ __forceinline__ void gemm_body(const float* __restrict__ A,
                                          const float* __restrict__ B,
                                          const float* __restrict__ bias,
                                          float* __restrict__ C) {
    __shared__ float Ast[32][68];   // [k][m]
    __shared__ float Bs[32][68];    // [k][n]
    const int tid = threadIdx.x;
    const int tx = tid & 15, ty = tid >> 4;
    const int m0 = blockIdx.y << 6, n0 = blockIdx.x << 6;
    float acc[4][4] = {};
    for (int k0 = 0; k0 < NFEAT; k0 += 32) {
        #pragma unroll
        for (int r = 0; r < 2; ++r) {
            int f4 = tid + (r << 8);
            // A tile: 64 rows(m) x 32 cols(k) -> 8 float4 per row
            int arow = f4 >> 3, acol = (f4 & 7) << 2;
            float4 av = *reinterpret_cast<const float4*>(
                &A[(size_t)(m0 + arow) * NFEAT + k0 + acol]);
            Ast[acol + 0][arow] = av.x;
            Ast[acol + 1][arow] = av.y;
            Ast[acol + 2][arow] = av.z;
            Ast[acol + 3][arow] = av.w;
            // B tile: 32 rows(k) x 64 cols(n) -> 16 float4 per row
            int brow = f4 >> 4, bcol = (f4 & 15) << 2;
            float4 bv = *reinterpret_cast<const float4*>(
                &B[(size_t)(k0 + brow) * NFEAT + n0 + bcol]);
            *reinterpret_cast<float4*>(&Bs[brow][bcol]) = bv;
        }
        __syncthreads();
        #pragma unroll
        for (int kk = 0; kk < 32; ++kk) {
            float4 a = *reinterpret_cast<const float4*>(&Ast[kk][ty << 2]);
            float4 b = *reinterpret_cast<const float4*>(&Bs[kk][tx << 2]);
            float av[4] = {a.x, a.y, a.z, a.w};
            float bw[4] = {b.x, b.y, b.z, b.w};
            #pragma unroll
            for (int i = 0; i < 4; ++i)
                #pragma unroll
                for (int j = 0; j < 4; ++j)
                    acc[i][j] += av[i] * bw[j];
        }
        __syncthreads();
    }
    #pragma unroll
    for (int i = 0; i < 4; ++i) {
        int m = m0 + (ty << 2) + i;
        #pragma unroll
        for (int j = 0; j < 4; ++j) {
            int n = n0 + (tx << 2) + j;
            C[(size_t)m * NFEAT + n] = acc[i][j] + bias[n];
        }
    }
}

__global__ __launch_bounds__(256) void qkv_kernel(
    const float* __restrict__ x,
    const float* __restrict__ Wq, const float* __restrict__ bq,
    const float* __restrict__ Wk, const float* __restrict__ bk,
    const float* __restrict__ Wv, const float* __restrict__ bv,
    float* __restrict__ q, float* __restrict__ kn, float* __restrict__ vn) {
    const float* B; const float* bias; float* C;
    if (blockIdx.z == 0)      { B = Wq; bias = bq; C = q;  }
    else if (blockIdx.z == 1) { B = Wk; bias = bk; C = kn; }
    else                      { B = Wv; bias = bv; C = vn; }
    gemm_body(x, B, bias, C);
}

__global__ __launch_bounds__(256) void out_kernel(
    const float* __restrict__ ctx,
    const float* __restrict__ Wo, const float* __restrict__ bo,
    float* __restrict__ out) {
    gemm_body(ctx, Wo, bo, out);
}

// ---------------------------------------------------------------------------
// Flash-style attention. One block per (64-query tile, head). 256 threads.
// Iterates over 64-key tiles of the (cache ++ new) key/value stream.
// LDS layouts chosen so every inner-loop read is a float4:
//   Qt[d][q], Kt[d][k], Vs[k][d], St[k][q]  (all padded to 68)
// Online softmax: per-query running max m_s / denom l_s in LDS.
// ---------------------------------------------------------------------------
__global__ __launch_bounds__(256) void attn_kernel(
    const float* __restrict__ qbuf, const float* __restrict__ knew,
    const float* __restrict__ vnew, const float* __restrict__ kcache,
    const float* __restrict__ vcache, const int* __restrict__ btab,
    const int* __restrict__ soff, float* __restrict__ ctx) {
    __shared__ float Qt[64][68];
    __shared__ float Kt[64][68];
    __shared__ float Vs[64][68];
    __shared__ float St[64][68];
    __shared__ float m_s[64], l_s[64], scale_s[64];
    __shared__ float pmax[64][4], psum[64][4];

    const int tid = threadIdx.x;
    const int tx = tid & 15, ty = tid >> 4;
    const int h = blockIdx.y;
    const int q0 = blockIdx.x << 6;
    const int offset = soff[0];
    const int total = offset + TCHUNK;
    const int ntiles = (total + 63) >> 6;

    // Stage Q (pre-scaled by 1/sqrt(DK) = 1/8), transposed to [d][q].
    #pragma unroll
    for (int r = 0; r < 4; ++r) {
        int f4 = tid + (r << 8);
        int row = f4 >> 4, col = (f4 & 15) << 2;   // row = query, col = d
        float4 v = *reinterpret_cast<const float4*>(
            &qbuf[(size_t)(q0 + row) * NFEAT + h * DK + col]);
        Qt[col + 0][row] = v.x * 0.125f;
        Qt[col + 1][row] = v.y * 0.125f;
        Qt[col + 2][row] = v.z * 0.125f;
        Qt[col + 3][row] = v.w * 0.125f;
    }
    if (tid < 64) { m_s[tid] = -1e30f; l_s[tid] = 0.f; }
    float acc[4][4] = {};
    __syncthreads();

    for (int t = 0; t < ntiles; ++t) {
        const int kt0 = t << 6;
        int nv = total - kt0; if (nv > 64) nv = 64;

        // Stage K (transposed) and V (natural) for 64 tokens.
        #pragma unroll
        for (int r = 0; r < 4; ++r) {
            int f4 = tid + (r << 8);
            int row = f4 >> 4, col = (f4 & 15) << 2;   // row = token, col = d
            int tok = kt0 + row;
            float4 kv, vv;
            if (tok < offset) {
                int phys = btab[tok >> 5];
                size_t base = ((size_t)(phys * 32 + (tok & 31)) * NHEAD + h) * DK + col;
                kv = *reinterpret_cast<const float4*>(&kcache[base]);
                vv = *reinterpret_cast<const float4*>(&vcache[base]);
            } else if (tok < total) {
                size_t base = (size_t)(tok - offset) * NFEAT + h * DK + col;
                kv = *reinterpret_cast<const float4*>(&knew[base]);
                vv = *reinterpret_cast<const float4*>(&vnew[base]);
            } else {
                kv = make_float4(0.f, 0.f, 0.f, 0.f);
                vv = make_float4(0.f, 0.f, 0.f, 0.f);
            }
            Kt[col + 0][row] = kv.x;
            Kt[col + 1][row] = kv.y;
            Kt[col + 2][row] = kv.z;
            Kt[col + 3][row] = kv.w;
            *reinterpret_cast<float4*>(&Vs[row][col]) = vv;
        }
        __syncthreads();

        // S tile: s[i][j] = sum_d Q[q0+ty*4+i][d] * K[kt0+tx*4+j][d]
        float s[4][4] = {};
        #pragma unroll
        for (int d = 0; d < 64; ++d) {
            float4 a = *reinterpret_cast<const float4*>(&Qt[d][ty << 2]);
            float4 b = *reinterpret_cast<const float4*>(&Kt[d][tx << 2]);
            float av[4] = {a.x, a.y, a.z, a.w};
            float bw[4] = {b.x, b.y, b.z, b.w};
            #pragma unroll
            for (int i = 0; i < 4; ++i)
                #pragma unroll
                for (int j = 0; j < 4; ++j)
                    s[i][j] += av[i] * bw[j];
        }
        #pragma unroll
        for (int j = 0; j < 4; ++j) {
            float4 w = make_float4(s[0][j], s[1][j], s[2][j], s[3][j]);
            *reinterpret_cast<float4*>(&St[(tx << 2) + j][ty << 2]) = w;
        }
        __syncthreads();

        // Partial row max (4 threads per query row).
        {
            int r = tid >> 2, c = tid & 3;
            float mx = -1e30f;
            for (int u = 0; u < 16; ++u) {
                int kidx = (c << 4) + u;
                if (kidx < nv) mx = fmaxf(mx, St[kidx][r]);
            }
            pmax[r][c] = mx;
        }
        __syncthreads();
        if (tid < 64) {
            float mo = m_s[tid];
            float mn = fmaxf(fmaxf(pmax[tid][0], pmax[tid][1]),
                             fmaxf(pmax[tid][2], pmax[tid][3]));
            mn = fmaxf(mo, mn);
            float sc = (mo <= -1e29f) ? 0.f : __expf(mo - mn);
            m_s[tid] = mn;
            scale_s[tid] = sc;
        }
        __syncthreads();
        // exp + partial sums, write P back into St.
        {
            int r = tid >> 2, c = tid & 3;
            float mn = m_s[r];
            float sum = 0.f;
            for (int u = 0; u < 16; ++u) {
                int kidx = (c << 4) + u;
                float p = 0.f;
                if (kidx < nv) p = __expf(St[kidx][r] - mn);
                St[kidx][r] = p;
                sum += p;
            }
            psum[r][c] = sum;
        }
        __syncthreads();
        if (tid < 64) {
            l_s[tid] = l_s[tid] * scale_s[tid] +
                       psum[tid][0] + psum[tid][1] + psum[tid][2] + psum[tid][3];
        }
        // Rescale accumulators and add P @ V.
        {
            float scl[4];
            #pragma unroll
            for (int i = 0; i < 4; ++i) scl[i] = scale_s[(ty << 2) + i];
            #pragma unroll
            for (int i = 0; i < 4; ++i)
                #pragma unroll
                for (int j = 0; j < 4; ++j)
                    acc[i][j] *= scl[i];
            #pragma unroll
            for (int kk = 0; kk < 64; ++kk) {
                float4 a = *reinterpret_cast<const float4*>(&St[kk][ty << 2]);
                float4 b = *reinterpret_cast<const float4*>(&Vs[kk][tx << 2]);
                float pv[4] = {a.x, a.y, a.z, a.w};
                float vw[4] = {b.x, b.y, b.z, b.w};
                #pragma unroll
                for (int i = 0; i < 4; ++i)
                    #pragma unroll
                    for (int j = 0; j < 4; ++j)
                        acc[i][j] += pv[i] * vw[j];
            }
        }
        __syncthreads();
    }

    // Normalize and store ctx in (t, h*64+d) layout for the output GEMM.
    #pragma unroll
    for (int i = 0; i < 4; ++i) {
        float inv = 1.f / l_s[(ty << 2) + i];
        int trow = q0 + (ty << 2) + i;
        #pragma unroll
        for (int j = 0; j < 4; ++j) {
            ctx[(size_t)trow * NFEAT + h * DK + (tx << 2) + j] = acc[i][j] * inv;
        }
    }
}

extern "C" void kernel_launch(void* const* d_in, const int* in_sizes, int n_in,
                              void* d_out, int out_size, void* d_ws, size_t ws_size,
                              hipStream_t stream) {
    const float* x   = (const float*)d_in[0];
    const float* Wq  = (const float*)d_in[1];
    const float* bq  = (const float*)d_in[2];
    const float* Wk  = (const float*)d_in[3];
    const float* bk  = (const float*)d_in[4];
    const float* Wv  = (const float*)d_in[5];
    const float* bv  = (const float*)d_in[6];
    const float* Wo  = (const float*)d_in[7];
    const float* bo  = (const float*)d_in[8];
    const float* kc  = (const float*)d_in[9];
    const float* vc  = (const float*)d_in[10];
    const int*   bt  = (const int*)d_in[11];
    const int*   so  = (const int*)d_in[12];

    float* q   = (float*)d_ws;                 // 1024x1024
    float* kn  = q  + (size_t)TCHUNK * NFEAT;  // 1024x1024
    float* vn  = kn + (size_t)TCHUNK * NFEAT;  // 1024x1024
    float* ctx = vn + (size_t)TCHUNK * NFEAT;  // 1024x1024

    qkv_kernel<<<dim3(16, 16, 3), 256, 0, stream>>>(x, Wq, bq, Wk, bk, Wv, bv,
                                                    q, kn, vn);
    attn_kernel<<<dim3(16, 16), 256, 0, stream>>>(q, kn, vn, kc, vc, bt, so, ctx);
    out_kernel<<<dim3(16, 16), 256, 0, stream>>>(ctx, Wo, bo, (float*)d_out);
}

// Round 3
// 272.756 us; speedup vs baseline: 2.3787x; 2.3787x over previous
//
#include <hip/hip_runtime.h>
#include <hip/hip_bf16.h>

#define NFEAT 1024
#define NHEAD 16
#define DK 64
#define TCHUNK 1024

using bf16x8 = __attribute__((ext_vector_type(8))) short;
using f32x4  = __attribute__((ext_vector_type(4))) float;

__device__ __forceinline__ short f2bf(float f) {
    __hip_bfloat16 h = __float2bfloat16(f);
    return *reinterpret_cast<short*>(&h);
}

// ---------------------------------------------------------------------------
// f32 GEMM: C[1024x1024] = (A @ B + bias) * oscale. 64x64 tile, BK=32,
// 256 threads, 4x4 acc/thread. Optional bf16 output (for Q/K/V).
// ---------------------------------------------------------------------------
template<bool BF16OUT>
__device__ __forceinline__ void gemm_body(const float* __restrict__ A,
                                          const float* __restrict__ B,
                                          const float* __restrict__ bias,
                                          void* __restrict__ Cout, float oscale) {
    __shared__ float Ast[32][68];   // [k][m]
    __shared__ float Bs[32][68];    // [k][n]
    const int tid = threadIdx.x;
    const int tx = tid & 15, ty = tid >> 4;
    const int m0 = blockIdx.y << 6, n0 = blockIdx.x << 6;
    float acc[4][4] = {};
    for (int k0 = 0; k0 < NFEAT; k0 += 32) {
        #pragma unroll
        for (int r = 0; r < 2; ++r) {
            int f4 = tid + (r << 8);
            int arow = f4 >> 3, acol = (f4 & 7) << 2;
            float4 av = *reinterpret_cast<const float4*>(
                &A[(size_t)(m0 + arow) * NFEAT + k0 + acol]);
            Ast[acol + 0][arow] = av.x;
            Ast[acol + 1][arow] = av.y;
            Ast[acol + 2][arow] = av.z;
            Ast[acol + 3][arow] = av.w;
            int brow = f4 >> 4, bcol = (f4 & 15) << 2;
            float4 bv = *reinterpret_cast<const float4*>(
                &B[(size_t)(k0 + brow) * NFEAT + n0 + bcol]);
            *reinterpret_cast<float4*>(&Bs[brow][bcol]) = bv;
        }
        __syncthreads();
        #pragma unroll
        for (int kk = 0; kk < 32; ++kk) {
            float4 a = *reinterpret_cast<const float4*>(&Ast[kk][ty << 2]);
            float4 b = *reinterpret_cast<const float4*>(&Bs[kk][tx << 2]);
            float av[4] = {a.x, a.y, a.z, a.w};
            float bw[4] = {b.x, b.y, b.z, b.w};
            #pragma unroll
            for (int i = 0; i < 4; ++i)
                #pragma unroll
                for (int j = 0; j < 4; ++j)
                    acc[i][j] += av[i] * bw[j];
        }
        __syncthreads();
    }
    #pragma unroll
    for (int i = 0; i < 4; ++i) {
        int m = m0 + (ty << 2) + i;
        if constexpr (BF16OUT) {
            __hip_bfloat16* C = (__hip_bfloat16*)Cout;
            short4 sv;
            int n = n0 + (tx << 2);
            sv.x = f2bf((acc[i][0] + bias[n + 0]) * oscale);
            sv.y = f2bf((acc[i][1] + bias[n + 1]) * oscale);
            sv.z = f2bf((acc[i][2] + bias[n + 2]) * oscale);
            sv.w = f2bf((acc[i][3] + bias[n + 3]) * oscale);
            *reinterpret_cast<short4*>(&C[(size_t)m * NFEAT + n]) = sv;
        } else {
            float* C = (float*)Cout;
            #pragma unroll
            for (int j = 0; j < 4; ++j) {
                int n = n0 + (tx << 2) + j;
                C[(size_t)m * NFEAT + n] = acc[i][j] + bias[n];
            }
        }
    }
}

__global__ __launch_bounds__(256) void qkv_kernel(
    const float* __restrict__ x,
    const float* __restrict__ Wq, const float* __restrict__ bq,
    const float* __restrict__ Wk, const float* __restrict__ bk,
    const float* __restrict__ Wv, const float* __restrict__ bv,
    __hip_bfloat16* __restrict__ q, __hip_bfloat16* __restrict__ kn,
    __hip_bfloat16* __restrict__ vn) {
    const float* B; const float* bias; __hip_bfloat16* C; float sc;
    if (blockIdx.z == 0)      { B = Wq; bias = bq; C = q;  sc = 0.125f; }
    else if (blockIdx.z == 1) { B = Wk; bias = bk; C = kn; sc = 1.0f;   }
    else                      { B = Wv; bias = bv; C = vn; sc = 1.0f;   }
    gemm_body<true>(x, B, bias, C, sc);
}

__global__ __launch_bounds__(256) void out_kernel(
    const float* __restrict__ ctx,
    const float* __restrict__ Wo, const float* __restrict__ bo,
    float* __restrict__ out) {
    gemm_body<false>(ctx, Wo, bo, out, 1.0f);
}

// ---------------------------------------------------------------------------
// MFMA flash attention. Block = 512 threads (8 waves), 64 queries x 1 head.
// Waves 0-3: even key-tiles, waves 4-7: odd key-tiles (2 waves/SIMD).
// MFMA 16x16x32 bf16: A-frag lane: [row=l&15][k=(l>>4)*8+e],
//                     B-frag lane: [k=(l>>4)*8+e][col=l&15],
//                     D    lane: [row=(l>>4)*4+r][col=l&15].
// S = Q*K^T: A=Q (regs, global), B=K (LDS natural [tok][d], stride 72 -> b128
// conflict-free). PV: A=P (per-wave LDS round trip), B=V^T (LDS [d][tok]).
// Online softmax per lane over 4 query rows; butterfly over 16 l15 lanes.
// ---------------------------------------------------------------------------
__global__ __launch_bounds__(512, 2) void attn_mfma(
    const __hip_bfloat16* __restrict__ qb,
    const __hip_bfloat16* __restrict__ knew,
    const __hip_bfloat16* __restrict__ vnew,
    const float* __restrict__ kcache, const float* __restrict__ vcache,
    const int* __restrict__ btab, const int* __restrict__ soff,
    float* __restrict__ ctx) {
    __shared__ short Ks[2][64][72];
    __shared__ short Vt[2][64][72];
    __shared__ short Ps[8][16][72];
    __shared__ float Macc[64][68];
    __shared__ float Mb_s[64], Lb_s[64];

    const int tid = threadIdx.x;
    const int lane = tid & 63;
    const int w = tid >> 6;
    const int l15 = lane & 15;
    const int lg = lane >> 4;
    const int qsub = w & 3;
    const int wph = w >> 2;
    const int h = blockIdx.y;
    const int q0 = blockIdx.x << 6;
    const int offset = soff[0];
    const int total = offset + TCHUNK;
    const int ntiles = (total + 63) >> 6;
    const int npairs = (ntiles + 1) >> 1;

    // staging role: thread covers token stok, d-range [sdseg, sdseg+16)
    const int sph = tid >> 8;
    const int stok = tid & 63;
    const int sdseg = ((tid >> 6) & 3) << 4;

    // Q A-fragments (queries q0 + qsub*16 + l15, pre-scaled by 1/8 upstream)
    const size_t qrow = (size_t)(q0 + qsub * 16 + l15) * NFEAT + h * DK;
    bf16x8 aq0 = *reinterpret_cast<const bf16x8*>(&qb[qrow + lg * 8]);
    bf16x8 aq1 = *reinterpret_cast<const bf16x8*>(&qb[qrow + 32 + lg * 8]);

    float m[4], lsum[4];
    f32x4 acc[4];
    #pragma unroll
    for (int r = 0; r < 4; ++r) { m[r] = -1e30f; lsum[r] = 0.f; }
    #pragma unroll
    for (int fc = 0; fc < 4; ++fc) acc[fc] = (f32x4){0.f, 0.f, 0.f, 0.f};

    for (int it = 0; it < npairs; ++it) {
        // ------------- stage K/V tile (2 tiles per iter, split by sph) ------
        int stile = 2 * it + sph;
        if (stile < ntiles) {
            int tok = (stile << 6) + stok;
            short kv16[16], vv16[16];
            if (tok < offset) {
                int phys = btab[tok >> 5];
                size_t base =
                    ((size_t)(phys * 32 + (tok & 31)) * NHEAD + h) * DK + sdseg;
                #pragma unroll
                for (int u = 0; u < 4; ++u) {
                    float4 kf = *reinterpret_cast<const float4*>(&kcache[base + u * 4]);
                    float4 vf = *reinterpret_cast<const float4*>(&vcache[base + u * 4]);
                    kv16[u * 4 + 0] = f2bf(kf.x); kv16[u * 4 + 1] = f2bf(kf.y);
                    kv16[u * 4 + 2] = f2bf(kf.z); kv16[u * 4 + 3] = f2bf(kf.w);
                    vv16[u * 4 + 0] = f2bf(vf.x); vv16[u * 4 + 1] = f2bf(vf.y);
                    vv16[u * 4 + 2] = f2bf(vf.z); vv16[u * 4 + 3] = f2bf(vf.w);
                }
            } else {
                size_t base = (size_t)(tok - offset) * NFEAT + h * DK + sdseg;
                bf16x8 k0 = *reinterpret_cast<const bf16x8*>(&knew[base]);
                bf16x8 k1 = *reinterpret_cast<const bf16x8*>(&knew[base + 8]);
                bf16x8 v0 = *reinterpret_cast<const bf16x8*>(&vnew[base]);
                bf16x8 v1 = *reinterpret_cast<const bf16x8*>(&vnew[base + 8]);
                #pragma unroll
                for (int e = 0; e < 8; ++e) {
                    kv16[e] = k0[e]; kv16[8 + e] = k1[e];
                    vv16[e] = v0[e]; vv16[8 + e] = v1[e];
                }
            }
            bf16x8 kp0, kp1;
            #pragma unroll
            for (int e = 0; e < 8; ++e) { kp0[e] = kv16[e]; kp1[e] = kv16[8 + e]; }
            *reinterpret_cast<bf16x8*>(&Ks[sph][stok][sdseg]) = kp0;
            *reinterpret_cast<bf16x8*>(&Ks[sph][stok][sdseg + 8]) = kp1;
            #pragma unroll
            for (int e = 0; e < 16; ++e) Vt[sph][sdseg + e][stok] = vv16[e];
        }
        __syncthreads();
        // ------------- compute this wave's phase tile ----------------------
        int ctile = 2 * it + wph;
        if (ctile < ntiles) {
            const int kt0 = ctile << 6;
            f32x4 s[4];
            #pragma unroll
            for (int fc = 0; fc < 4; ++fc) s[fc] = (f32x4){0.f, 0.f, 0.f, 0.f};
            #pragma unroll
            for (int fc = 0; fc < 4; ++fc) {
                bf16x8 b0 = *reinterpret_cast<const bf16x8*>(
                    &Ks[wph][fc * 16 + l15][lg * 8]);
                bf16x8 b1 = *reinterpret_cast<const bf16x8*>(
                    &Ks[wph][fc * 16 + l15][32 + lg * 8]);
                s[fc] = __builtin_amdgcn_mfma_f32_16x16x32_bf16(aq0, b0, s[fc], 0, 0, 0);
                s[fc] = __builtin_amdgcn_mfma_f32_16x16x32_bf16(aq1, b1, s[fc], 0, 0, 0);
            }
            // mask + online softmax (per lane: 4 query rows x 4 key cols)
            float tmax[4] = {-1e30f, -1e30f, -1e30f, -1e30f};
            #pragma unroll
            for (int fc = 0; fc < 4; ++fc) {
                bool valid = (kt0 + fc * 16 + l15) < total;
                #pragma unroll
                for (int r = 0; r < 4; ++r) {
                    float v = valid ? s[fc][r] : -1e30f;
                    s[fc][r] = v;
                    tmax[r] = fmaxf(tmax[r], v);
                }
            }
            #pragma unroll
            for (int r = 0; r < 4; ++r) {
                tmax[r] = fmaxf(tmax[r], __shfl_xor(tmax[r], 1, 64));
                tmax[r] = fmaxf(tmax[r], __shfl_xor(tmax[r], 2, 64));
                tmax[r] = fmaxf(tmax[r], __shfl_xor(tmax[r], 4, 64));
                tmax[r] = fmaxf(tmax[r], __shfl_xor(tmax[r], 8, 64));
            }
            float ts[4];
            #pragma unroll
            for (int r = 0; r < 4; ++r) {
                float mn = fmaxf(m[r], tmax[r]);
                float sc = __expf(m[r] - mn);
                m[r] = mn;
                lsum[r] *= sc;
                #pragma unroll
                for (int fc = 0; fc < 4; ++fc) acc[fc][r] *= sc;
                ts[r] = 0.f;
                #pragma unroll
                for (int fc = 0; fc < 4; ++fc) {
                    float p = __expf(s[fc][r] - mn);
                    s[fc][r] = p;
                    ts[r] += p;
                }
            }
            #pragma unroll
            for (int r = 0; r < 4; ++r) {
                ts[r] += __shfl_xor(ts[r], 1, 64);
                ts[r] += __shfl_xor(ts[r], 2, 64);
                ts[r] += __shfl_xor(ts[r], 4, 64);
                ts[r] += __shfl_xor(ts[r], 8, 64);
                lsum[r] += ts[r];
            }
            // P -> per-wave LDS (D layout -> A-frag layout), then PV
            #pragma unroll
            for (int fc = 0; fc < 4; ++fc)
                #pragma unroll
                for (int r = 0; r < 4; ++r)
                    Ps[w][lg * 4 + r][l15 + 16 * fc] = f2bf(s[fc][r]);
            #pragma unroll
            for (int ks = 0; ks < 2; ++ks) {
                bf16x8 pa = *reinterpret_cast<const bf16x8*>(
                    &Ps[w][l15][ks * 32 + lg * 8]);
                #pragma unroll
                for (int fc = 0; fc < 4; ++fc) {
                    bf16x8 bv = *reinterpret_cast<const bf16x8*>(
                        &Vt[wph][l15 + 16 * fc][ks * 32 + lg * 8]);
                    acc[fc] = __builtin_amdgcn_mfma_f32_16x16x32_bf16(pa, bv, acc[fc], 0, 0, 0);
                }
            }
        }
        __syncthreads();
    }

    // ------------- merge phase 1 into phase 0, write ctx -------------------
    if (wph == 1) {
        if (l15 == 0) {
            #pragma unroll
            for (int r = 0; r < 4; ++r) {
                Mb_s[qsub * 16 + lg * 4 + r] = m[r];
                Lb_s[qsub * 16 + lg * 4 + r] = lsum[r];
            }
        }
        #pragma unroll
        for (int fc = 0; fc < 4; ++fc)
            #pragma unroll
            for (int r = 0; r < 4; ++r)
                Macc[qsub * 16 + lg * 4 + r][l15 + 16 * fc] = acc[fc][r];
    }
    __syncthreads();
    if (wph == 0) {
        #pragma unroll
        for (int r = 0; r < 4; ++r) {
            int q = qsub * 16 + lg * 4 + r;
            float mb = Mb_s[q], lb = Lb_s[q];
            float M = fmaxf(m[r], mb);
            float ea = __expf(m[r] - M), eb = __expf(mb - M);
            float inv = 1.f / (lsum[r] * ea + lb * eb);
            #pragma unroll
            for (int fc = 0; fc < 4; ++fc) {
                float v = (acc[fc][r] * ea + Macc[q][l15 + 16 * fc] * eb) * inv;
                ctx[(size_t)(q0 + q) * NFEAT + h * DK + l15 + 16 * fc] = v;
            }
        }
    }
}

extern "C" void kernel_launch(void* const* d_in, const int* in_sizes, int n_in,
                              void* d_out, int out_size, void* d_ws, size_t ws_size,
                              hipStream_t stream) {
    const float* x   = (const float*)d_in[0];
    const float* Wq  = (const float*)d_in[1];
    const float* bq  = (const float*)d_in[2];
    const float* Wk  = (const float*)d_in[3];
    const float* bk  = (const float*)d_in[4];
    const float* Wv  = (const float*)d_in[5];
    const float* bv  = (const float*)d_in[6];
    const float* Wo  = (const float*)d_in[7];
    const float* bo  = (const float*)d_in[8];
    const float* kc  = (const float*)d_in[9];
    const float* vc  = (const float*)d_in[10];
    const int*   bt  = (const int*)d_in[11];
    const int*   so  = (const int*)d_in[12];

    __hip_bfloat16* qbf = (__hip_bfloat16*)d_ws;                    // 1M bf16
    __hip_bfloat16* knb = qbf + (size_t)TCHUNK * NFEAT;             // 1M bf16
    __hip_bfloat16* vnb = knb + (size_t)TCHUNK * NFEAT;             // 1M bf16
    float* ctx = (float*)(vnb + (size_t)TCHUNK * NFEAT);            // 1M f32

    qkv_kernel<<<dim3(16, 16, 3), 256, 0, stream>>>(x, Wq, bq, Wk, bk, Wv, bv,
                                                    qbf, knb, vnb);
    attn_mfma<<<dim3(16, 16), 512, 0, stream>>>(qbf, knb, vnb, kc, vc, bt, so, ctx);
    out_kernel<<<dim3(16, 16), 256, 0, stream>>>(ctx, Wo, bo, (float*)d_out);
}

// Round 4
// 126.902 us; speedup vs baseline: 5.1127x; 2.1493x over previous
//
#include <hip/hip_runtime.h>
#include <hip/hip_bf16.h>

#define NFEAT 1024
#define NHEAD 16
#define DK 64
#define TCHUNK 1024
#define MAXTOK 4096

using bf16x8 = __attribute__((ext_vector_type(8))) short;
using f32x4  = __attribute__((ext_vector_type(4))) float;

__device__ __forceinline__ short f2bf(float f) {
    __hip_bfloat16 h = __float2bfloat16(f);
    return *reinterpret_cast<short*>(&h);
}

// ---------------------------------------------------------------------------
// pack: blocks [0,1024): transpose+convert W{q,k,v,o} -> Wt[4096 n][1024 k] bf16
//       blocks [1024,1152): convert x -> xb bf16
// ---------------------------------------------------------------------------
__global__ __launch_bounds__(256) void pack_kernel(
    const float* __restrict__ x,
    const float* __restrict__ Wq, const float* __restrict__ Wk,
    const float* __restrict__ Wv, const float* __restrict__ Wo,
    short* __restrict__ xb, short* __restrict__ Wt) {
    const int b = blockIdx.x;
    const int t = threadIdx.x;
    if (b < 1024) {
        __shared__ short T[64][72];
        const int w = b >> 8, tile = b & 255;
        const int k0 = (tile >> 4) << 6, n0 = (tile & 15) << 6;
        const float* W = (w == 0) ? Wq : (w == 1) ? Wk : (w == 2) ? Wv : Wo;
        const int r = t >> 2, cs = (t & 3) << 4;
        #pragma unroll
        for (int u = 0; u < 4; ++u) {
            float4 v = *reinterpret_cast<const float4*>(
                &W[(size_t)(k0 + r) * NFEAT + n0 + cs + u * 4]);
            T[cs + u * 4 + 0][r] = f2bf(v.x);
            T[cs + u * 4 + 1][r] = f2bf(v.y);
            T[cs + u * 4 + 2][r] = f2bf(v.z);
            T[cs + u * 4 + 3][r] = f2bf(v.w);
        }
        __syncthreads();
        const int c = t >> 2, rs = (t & 3) << 4;
        bf16x8 a0 = *reinterpret_cast<const bf16x8*>(&T[c][rs]);
        bf16x8 a1 = *reinterpret_cast<const bf16x8*>(&T[c][rs + 8]);
        size_t drow = (size_t)(w * 1024 + n0 + c) * NFEAT + k0 + rs;
        *reinterpret_cast<bf16x8*>(&Wt[drow]) = a0;
        *reinterpret_cast<bf16x8*>(&Wt[drow + 8]) = a1;
    } else {
        const int e0 = ((b - 1024) * 256 + t) * 32;
        #pragma unroll
        for (int u = 0; u < 4; ++u) {
            float4 v0 = *reinterpret_cast<const float4*>(&x[e0 + u * 8]);
            float4 v1 = *reinterpret_cast<const float4*>(&x[e0 + u * 8 + 4]);
            bf16x8 o;
            o[0] = f2bf(v0.x); o[1] = f2bf(v0.y); o[2] = f2bf(v0.z); o[3] = f2bf(v0.w);
            o[4] = f2bf(v1.x); o[5] = f2bf(v1.y); o[6] = f2bf(v1.z); o[7] = f2bf(v1.w);
            *reinterpret_cast<bf16x8*>(&xb[e0 + u * 8]) = o;
        }
    }
}

// ---------------------------------------------------------------------------
// QKV MFMA GEMM: qkvb[1024 t][3072] = xb @ Wqkv + bias (Q cols scaled 1/8).
// BM=64 BN=128 BK=64, 256 thr (4 waves in 2x2), wave tile 32x64 (2x4 frags).
// A and B both read as [row][k] bf16 from LDS (pad 72).
// ---------------------------------------------------------------------------
__global__ __launch_bounds__(256) void qkv_gemm(
    const short* __restrict__ xb, const short* __restrict__ Wt,
    const float* __restrict__ bq, const float* __restrict__ bk,
    const float* __restrict__ bv, short* __restrict__ qkvb) {
    __shared__ short As[64][72];
    __shared__ short Bs[128][72];
    const int tid = threadIdx.x;
    const int lane = tid & 63;
    const int w = tid >> 6;
    const int l15 = lane & 15, lg = lane >> 4;
    const int wr = w >> 1, wc = w & 1;
    const int m0 = blockIdx.y << 6, n0 = blockIdx.x << 7;
    const int sel = n0 >> 10;
    const float* bias = (sel == 0) ? bq : (sel == 1) ? bk : bv;
    const float oscale = (sel == 0) ? 0.125f : 1.0f;

    f32x4 acc[2][4];
    #pragma unroll
    for (int i = 0; i < 2; ++i)
        #pragma unroll
        for (int j = 0; j < 4; ++j) acc[i][j] = (f32x4){0.f, 0.f, 0.f, 0.f};

    for (int k0 = 0; k0 < NFEAT; k0 += 64) {
        #pragma unroll
        for (int r = 0; r < 2; ++r) {
            int f = tid + (r << 8);
            int row = f >> 3, kc = (f & 7) << 3;
            *reinterpret_cast<bf16x8*>(&As[row][kc]) =
                *reinterpret_cast<const bf16x8*>(&xb[(size_t)(m0 + row) * NFEAT + k0 + kc]);
        }
        #pragma unroll
        for (int r = 0; r < 4; ++r) {
            int f = tid + (r << 8);
            int row = f >> 3, kc = (f & 7) << 3;
            *reinterpret_cast<bf16x8*>(&Bs[row][kc]) =
                *reinterpret_cast<const bf16x8*>(&Wt[(size_t)(n0 + row) * NFEAT + k0 + kc]);
        }
        __syncthreads();
        #pragma unroll
        for (int kk = 0; kk < 2; ++kk) {
            bf16x8 am[2], bn[4];
            #pragma unroll
            for (int mi = 0; mi < 2; ++mi)
                am[mi] = *reinterpret_cast<const bf16x8*>(
                    &As[wr * 32 + mi * 16 + l15][kk * 32 + lg * 8]);
            #pragma unroll
            for (int ni = 0; ni < 4; ++ni)
                bn[ni] = *reinterpret_cast<const bf16x8*>(
                    &Bs[wc * 64 + ni * 16 + l15][kk * 32 + lg * 8]);
            #pragma unroll
            for (int mi = 0; mi < 2; ++mi)
                #pragma unroll
                for (int ni = 0; ni < 4; ++ni)
                    acc[mi][ni] = __builtin_amdgcn_mfma_f32_16x16x32_bf16(
                        am[mi], bn[ni], acc[mi][ni], 0, 0, 0);
        }
        __syncthreads();
    }
    #pragma unroll
    for (int mi = 0; mi < 2; ++mi)
        #pragma unroll
        for (int rr = 0; rr < 4; ++rr) {
            int m = m0 + wr * 32 + mi * 16 + lg * 4 + rr;
            #pragma unroll
            for (int ni = 0; ni < 4; ++ni) {
                int n = n0 + wc * 64 + ni * 16 + l15;
                float v = (acc[mi][ni][rr] + bias[n & 1023]) * oscale;
                qkvb[(size_t)m * 3072 + n] = f2bf(v);
            }
        }
}

// ---------------------------------------------------------------------------
// Output MFMA GEMM: out[1024][1024] f32 = ctxb @ Wo + bo.
// BM=64 BN=64 BK=64, wave tile 32x32.
// ---------------------------------------------------------------------------
__global__ __launch_bounds__(256) void out_gemm(
    const short* __restrict__ ctxb, const short* __restrict__ Wt,
    const float* __restrict__ bo, float* __restrict__ out) {
    __shared__ short As[64][72];
    __shared__ short Bs[64][72];
    const int tid = threadIdx.x;
    const int lane = tid & 63;
    const int w = tid >> 6;
    const int l15 = lane & 15, lg = lane >> 4;
    const int wr = w >> 1, wc = w & 1;
    const int m0 = blockIdx.y << 6, n0 = blockIdx.x << 6;

    f32x4 acc[2][2];
    #pragma unroll
    for (int i = 0; i < 2; ++i)
        #pragma unroll
        for (int j = 0; j < 2; ++j) acc[i][j] = (f32x4){0.f, 0.f, 0.f, 0.f};

    for (int k0 = 0; k0 < NFEAT; k0 += 64) {
        #pragma unroll
        for (int r = 0; r < 2; ++r) {
            int f = tid + (r << 8);
            int row = f >> 3, kc = (f & 7) << 3;
            *reinterpret_cast<bf16x8*>(&As[row][kc]) =
                *reinterpret_cast<const bf16x8*>(&ctxb[(size_t)(m0 + row) * NFEAT + k0 + kc]);
            *reinterpret_cast<bf16x8*>(&Bs[row][kc]) =
                *reinterpret_cast<const bf16x8*>(
                    &Wt[(size_t)(3072 + n0 + row) * NFEAT + k0 + kc]);
        }
        __syncthreads();
        #pragma unroll
        for (int kk = 0; kk < 2; ++kk) {
            bf16x8 am[2], bn[2];
            #pragma unroll
            for (int mi = 0; mi < 2; ++mi)
                am[mi] = *reinterpret_cast<const bf16x8*>(
                    &As[wr * 32 + mi * 16 + l15][kk * 32 + lg * 8]);
            #pragma unroll
            for (int ni = 0; ni < 2; ++ni)
                bn[ni] = *reinterpret_cast<const bf16x8*>(
                    &Bs[wc * 32 + ni * 16 + l15][kk * 32 + lg * 8]);
            #pragma unroll
            for (int mi = 0; mi < 2; ++mi)
                #pragma unroll
                for (int ni = 0; ni < 2; ++ni)
                    acc[mi][ni] = __builtin_amdgcn_mfma_f32_16x16x32_bf16(
                        am[mi], bn[ni], acc[mi][ni], 0, 0, 0);
        }
        __syncthreads();
    }
    #pragma unroll
    for (int mi = 0; mi < 2; ++mi)
        #pragma unroll
        for (int rr = 0; rr < 4; ++rr) {
            int m = m0 + wr * 32 + mi * 16 + lg * 4 + rr;
            #pragma unroll
            for (int ni = 0; ni < 2; ++ni) {
                int n = n0 + wc * 32 + ni * 16 + l15;
                out[(size_t)m * NFEAT + n] = acc[mi][ni][rr] + bo[n];
            }
        }
}

// ---------------------------------------------------------------------------
// gather: build kg[16 h][4096 tok][64 d] bf16 and vt[16 h][64 d][4096 tok]
// bf16 from the paged f32 cache (tok < offset) and qkvb's K/V columns
// (offset <= tok < total). Zero-fill tok >= total.
// ---------------------------------------------------------------------------
__global__ __launch_bounds__(256) void gather_kv(
    const float* __restrict__ kc, const float* __restrict__ vc,
    const short* __restrict__ qkvb, const int* __restrict__ btab,
    const int* __restrict__ soff, short* __restrict__ kg, short* __restrict__ vt) {
    __shared__ short TV[64][72];
    const int h = blockIdx.x;
    const int t0 = blockIdx.y << 6;
    const int offset = soff[0], total = offset + TCHUNK;
    const int t = threadIdx.x;
    const int row = t >> 2, ds = (t & 3) << 4;
    const int tok = t0 + row;
    short kv[16], vv[16];
    if (tok < offset) {
        int phys = btab[tok >> 5];
        size_t base = ((size_t)(phys * 32 + (tok & 31)) * NHEAD + h) * DK + ds;
        #pragma unroll
        for (int u = 0; u < 4; ++u) {
            float4 kf = *reinterpret_cast<const float4*>(&kc[base + u * 4]);
            float4 vf = *reinterpret_cast<const float4*>(&vc[base + u * 4]);
            kv[u * 4 + 0] = f2bf(kf.x); kv[u * 4 + 1] = f2bf(kf.y);
            kv[u * 4 + 2] = f2bf(kf.z); kv[u * 4 + 3] = f2bf(kf.w);
            vv[u * 4 + 0] = f2bf(vf.x); vv[u * 4 + 1] = f2bf(vf.y);
            vv[u * 4 + 2] = f2bf(vf.z); vv[u * 4 + 3] = f2bf(vf.w);
        }
    } else if (tok < total) {
        size_t base = (size_t)(tok - offset) * 3072 + 1024 + h * DK + ds;
        bf16x8 k0 = *reinterpret_cast<const bf16x8*>(&qkvb[base]);
        bf16x8 k1 = *reinterpret_cast<const bf16x8*>(&qkvb[base + 8]);
        bf16x8 v0 = *reinterpret_cast<const bf16x8*>(&qkvb[base + 1024]);
        bf16x8 v1 = *reinterpret_cast<const bf16x8*>(&qkvb[base + 1032]);
        #pragma unroll
        for (int e = 0; e < 8; ++e) {
            kv[e] = k0[e]; kv[8 + e] = k1[e];
            vv[e] = v0[e]; vv[8 + e] = v1[e];
        }
    } else {
        #pragma unroll
        for (int e = 0; e < 16; ++e) { kv[e] = 0; vv[e] = 0; }
    }
    // K: direct write
    {
        bf16x8 a, b;
        #pragma unroll
        for (int e = 0; e < 8; ++e) { a[e] = kv[e]; b[e] = kv[8 + e]; }
        size_t kb = ((size_t)h * MAXTOK + tok) * DK + ds;
        *reinterpret_cast<bf16x8*>(&kg[kb]) = a;
        *reinterpret_cast<bf16x8*>(&kg[kb + 8]) = b;
    }
    // V: transpose via LDS
    #pragma unroll
    for (int e = 0; e < 16; ++e) TV[ds + e][row] = vv[e];
    __syncthreads();
    {
        const int d = t >> 2, ts = (t & 3) << 4;
        bf16x8 a = *reinterpret_cast<const bf16x8*>(&TV[d][ts]);
        bf16x8 b = *reinterpret_cast<const bf16x8*>(&TV[d][ts + 8]);
        size_t vb = ((size_t)h * DK + d) * MAXTOK + t0 + ts;
        *reinterpret_cast<bf16x8*>(&vt[vb]) = a;
        *reinterpret_cast<bf16x8*>(&vt[vb + 8]) = b;
    }
}

// ---------------------------------------------------------------------------
// MFMA flash attention with KV-split. Grid (x=head, y=qtile, z=split(2)).
// All blocks of head h land on XCD h%8 -> KV slice (2 MB bf16) stays in L2.
// Block = 512 thr (8 waves): waves 0-3 even tiles, 4-7 odd tiles of this
// split's 32-tile range; in-block phase merge, per-split partial to pacc.
// ---------------------------------------------------------------------------
__global__ __launch_bounds__(512, 2) void attn_mfma(
    const short* __restrict__ qkvb, const short* __restrict__ kg,
    const short* __restrict__ vt, const int* __restrict__ soff,
    float* __restrict__ pacc) {
    __shared__ short Ks[2][64][72];
    __shared__ short Vt[2][64][72];
    __shared__ short Ps[8][16][72];
    __shared__ float Macc[64][68];
    __shared__ float Mb_s[64], Lb_s[64];

    const int tid = threadIdx.x;
    const int lane = tid & 63;
    const int w = tid >> 6;
    const int l15 = lane & 15;
    const int lg = lane >> 4;
    const int qsub = w & 3;
    const int wph = w >> 2;
    const int h = blockIdx.x;
    const int q0 = blockIdx.y << 6;
    const int z = blockIdx.z;
    const int offset = soff[0];
    const int total = offset + TCHUNK;
    const int ntiles = (total + 63) >> 6;
    const int tbase = z << 5;
    const int tend = min(tbase + 32, ntiles);

    const int sph = tid >> 8;
    const int srow = (tid >> 2) & 63;
    const int sds = (tid & 3) << 4;

    const short* kbase = kg + (size_t)h * MAXTOK * DK;
    const short* vbase = vt + (size_t)h * DK * MAXTOK;

    const size_t qrow = (size_t)(q0 + qsub * 16 + l15) * 3072 + h * DK;
    bf16x8 aq0 = *reinterpret_cast<const bf16x8*>(&qkvb[qrow + lg * 8]);
    bf16x8 aq1 = *reinterpret_cast<const bf16x8*>(&qkvb[qrow + 32 + lg * 8]);

    float m[4], lsum[4];
    f32x4 acc[4];
    #pragma unroll
    for (int r = 0; r < 4; ++r) { m[r] = -1e30f; lsum[r] = 0.f; }
    #pragma unroll
    for (int fc = 0; fc < 4; ++fc) acc[fc] = (f32x4){0.f, 0.f, 0.f, 0.f};

    for (int it = 0; it < 16; ++it) {
        const int stile = tbase + 2 * it + sph;
        if (stile < tend) {
            const int tok0 = stile << 6;
            size_t kb = ((size_t)(tok0 + srow)) * DK + sds;
            *reinterpret_cast<bf16x8*>(&Ks[sph][srow][sds]) =
                *reinterpret_cast<const bf16x8*>(&kbase[kb]);
            *reinterpret_cast<bf16x8*>(&Ks[sph][srow][sds + 8]) =
                *reinterpret_cast<const bf16x8*>(&kbase[kb + 8]);
            size_t vb = (size_t)srow * MAXTOK + tok0 + sds;
            *reinterpret_cast<bf16x8*>(&Vt[sph][srow][sds]) =
                *reinterpret_cast<const bf16x8*>(&vbase[vb]);
            *reinterpret_cast<bf16x8*>(&Vt[sph][srow][sds + 8]) =
                *reinterpret_cast<const bf16x8*>(&vbase[vb + 8]);
        }
        __syncthreads();
        const int ctile = tbase + 2 * it + wph;
        if (ctile < tend) {
            const int kt0 = ctile << 6;
            f32x4 s[4];
            #pragma unroll
            for (int fc = 0; fc < 4; ++fc) s[fc] = (f32x4){0.f, 0.f, 0.f, 0.f};
            #pragma unroll
            for (int fc = 0; fc < 4; ++fc) {
                bf16x8 b0 = *reinterpret_cast<const bf16x8*>(
                    &Ks[wph][fc * 16 + l15][lg * 8]);
                bf16x8 b1 = *reinterpret_cast<const bf16x8*>(
                    &Ks[wph][fc * 16 + l15][32 + lg * 8]);
                s[fc] = __builtin_amdgcn_mfma_f32_16x16x32_bf16(aq0, b0, s[fc], 0, 0, 0);
                s[fc] = __builtin_amdgcn_mfma_f32_16x16x32_bf16(aq1, b1, s[fc], 0, 0, 0);
            }
            float tmax[4] = {-1e30f, -1e30f, -1e30f, -1e30f};
            #pragma unroll
            for (int fc = 0; fc < 4; ++fc) {
                bool valid = (kt0 + fc * 16 + l15) < total;
                #pragma unroll
                for (int r = 0; r < 4; ++r) {
                    float v = valid ? s[fc][r] : -1e30f;
                    s[fc][r] = v;
                    tmax[r] = fmaxf(tmax[r], v);
                }
            }
            #pragma unroll
            for (int r = 0; r < 4; ++r) {
                tmax[r] = fmaxf(tmax[r], __shfl_xor(tmax[r], 1, 64));
                tmax[r] = fmaxf(tmax[r], __shfl_xor(tmax[r], 2, 64));
                tmax[r] = fmaxf(tmax[r], __shfl_xor(tmax[r], 4, 64));
                tmax[r] = fmaxf(tmax[r], __shfl_xor(tmax[r], 8, 64));
            }
            float ts[4];
            #pragma unroll
            for (int r = 0; r < 4; ++r) {
                float mn = fmaxf(m[r], tmax[r]);
                float sc = __expf(m[r] - mn);
                m[r] = mn;
                lsum[r] *= sc;
                #pragma unroll
                for (int fc = 0; fc < 4; ++fc) acc[fc][r] *= sc;
                ts[r] = 0.f;
                #pragma unroll
                for (int fc = 0; fc < 4; ++fc) {
                    float p = __expf(s[fc][r] - mn);
                    s[fc][r] = p;
                    ts[r] += p;
                }
            }
            #pragma unroll
            for (int r = 0; r < 4; ++r) {
                ts[r] += __shfl_xor(ts[r], 1, 64);
                ts[r] += __shfl_xor(ts[r], 2, 64);
                ts[r] += __shfl_xor(ts[r], 4, 64);
                ts[r] += __shfl_xor(ts[r], 8, 64);
                lsum[r] += ts[r];
            }
            #pragma unroll
            for (int fc = 0; fc < 4; ++fc)
                #pragma unroll
                for (int r = 0; r < 4; ++r)
                    Ps[w][lg * 4 + r][l15 + 16 * fc] = f2bf(s[fc][r]);
            #pragma unroll
            for (int ks = 0; ks < 2; ++ks) {
                bf16x8 pa = *reinterpret_cast<const bf16x8*>(
                    &Ps[w][l15][ks * 32 + lg * 8]);
                #pragma unroll
                for (int fc = 0; fc < 4; ++fc) {
                    bf16x8 bv = *reinterpret_cast<const bf16x8*>(
                        &Vt[wph][l15 + 16 * fc][ks * 32 + lg * 8]);
                    acc[fc] = __builtin_amdgcn_mfma_f32_16x16x32_bf16(pa, bv, acc[fc], 0, 0, 0);
                }
            }
        }
        __syncthreads();
    }

    // in-block phase merge, then write this split's partial (unnormalized)
    if (wph == 1) {
        if (l15 == 0) {
            #pragma unroll
            for (int r = 0; r < 4; ++r) {
                Mb_s[qsub * 16 + lg * 4 + r] = m[r];
                Lb_s[qsub * 16 + lg * 4 + r] = lsum[r];
            }
        }
        #pragma unroll
        for (int fc = 0; fc < 4; ++fc)
            #pragma unroll
            for (int r = 0; r < 4; ++r)
                Macc[qsub * 16 + lg * 4 + r][l15 + 16 * fc] = acc[fc][r];
    }
    __syncthreads();
    if (wph == 0) {
        const size_t pbase =
            (((size_t)z * NHEAD + h) * 16 + blockIdx.y) * 4224;
        #pragma unroll
        for (int r = 0; r < 4; ++r) {
            int q = qsub * 16 + lg * 4 + r;
            float mb = Mb_s[q], lb = Lb_s[q];
            float M = fmaxf(m[r], mb);
            float ea = __expf(m[r] - M), eb = __expf(mb - M);
            if (l15 == 0) {
                pacc[pbase + 4096 + q] = M;
                pacc[pbase + 4160 + q] = lsum[r] * ea + lb * eb;
            }
            #pragma unroll
            for (int fc = 0; fc < 4; ++fc) {
                pacc[pbase + q * 64 + l15 + 16 * fc] =
                    acc[fc][r] * ea + Macc[q][l15 + 16 * fc] * eb;
            }
        }
    }
}

// ---------------------------------------------------------------------------
// merge the 2 split partials -> ctxb bf16 [1024 t][1024 (h*64+d)]
// ---------------------------------------------------------------------------
__global__ __launch_bounds__(256) void merge_ctx(
    const float* __restrict__ pacc, short* __restrict__ ctxb) {
    const int h = blockIdx.x, qt = blockIdx.y;
    const int t = threadIdx.x;
    const int q = t >> 2, ds = (t & 3) << 4;
    const size_t b0 = (((size_t)0 * NHEAD + h) * 16 + qt) * 4224;
    const size_t b1 = (((size_t)1 * NHEAD + h) * 16 + qt) * 4224;
    float m0 = pacc[b0 + 4096 + q], l0 = pacc[b0 + 4160 + q];
    float m1 = pacc[b1 + 4096 + q], l1 = pacc[b1 + 4160 + q];
    float M = fmaxf(m0, m1);
    float e0 = __expf(m0 - M), e1 = __expf(m1 - M);
    float inv = 1.f / (l0 * e0 + l1 * e1);
    bf16x8 o0, o1;
    #pragma unroll
    for (int j = 0; j < 8; ++j) {
        float v = (pacc[b0 + q * 64 + ds + j] * e0 +
                   pacc[b1 + q * 64 + ds + j] * e1) * inv;
        o0[j] = f2bf(v);
    }
    #pragma unroll
    for (int j = 0; j < 8; ++j) {
        float v = (pacc[b0 + q * 64 + ds + 8 + j] * e0 +
                   pacc[b1 + q * 64 + ds + 8 + j] * e1) * inv;
        o1[j] = f2bf(v);
    }
    size_t ob = (size_t)(qt * 64 + q) * NFEAT + h * DK + ds;
    *reinterpret_cast<bf16x8*>(&ctxb[ob]) = o0;
    *reinterpret_cast<bf16x8*>(&ctxb[ob + 8]) = o1;
}

extern "C" void kernel_launch(void* const* d_in, const int* in_sizes, int n_in,
                              void* d_out, int out_size, void* d_ws, size_t ws_size,
                              hipStream_t stream) {
    const float* x   = (const float*)d_in[0];
    const float* Wq  = (const float*)d_in[1];
    const float* bq  = (const float*)d_in[2];
    const float* Wk  = (const float*)d_in[3];
    const float* bk  = (const float*)d_in[4];
    const float* Wv  = (const float*)d_in[5];
    const float* bv  = (const float*)d_in[6];
    const float* Wo  = (const float*)d_in[7];
    const float* bo  = (const float*)d_in[8];
    const float* kc  = (const float*)d_in[9];
    const float* vc  = (const float*)d_in[10];
    const int*   bt  = (const int*)d_in[11];
    const int*   so  = (const int*)d_in[12];

    short* xb   = (short*)d_ws;                       // 1M bf16
    short* Wt   = xb + (size_t)1024 * 1024;           // 4M bf16
    short* qkvb = Wt + (size_t)4096 * 1024;           // 3M bf16
    short* kg   = qkvb + (size_t)1024 * 3072;         // 4M bf16
    short* vtb  = kg + (size_t)NHEAD * MAXTOK * DK;   // 4M bf16
    float* pacc = (float*)(vtb + (size_t)NHEAD * DK * MAXTOK);  // 2*256*4224 f32
    short* ctxb = (short*)(pacc + (size_t)2 * 256 * 4224);      // 1M bf16

    pack_kernel<<<dim3(1152), 256, 0, stream>>>(x, Wq, Wk, Wv, Wo, xb, Wt);
    qkv_gemm<<<dim3(24, 16), 256, 0, stream>>>(xb, Wt, bq, bk, bv, qkvb);
    gather_kv<<<dim3(16, 64), 256, 0, stream>>>(kc, vc, qkvb, bt, so, kg, vtb);
    attn_mfma<<<dim3(16, 16, 2), 512, 0, stream>>>(qkvb, kg, vtb, so, pacc);
    merge_ctx<<<dim3(16, 16), 256, 0, stream>>>(pacc, ctxb);
    out_gemm<<<dim3(16, 16), 256, 0, stream>>>(ctxb, Wt, bo, (float*)d_out);
}

// Round 6
// 105.217 us; speedup vs baseline: 6.1664x; 1.2061x over previous
//
#include <hip/hip_runtime.h>
#include <hip/hip_bf16.h>

#define NFEAT 1024
#define NHEAD 16
#define DK 64
#define TCHUNK 1024
#define MAXTOK 4096
#define NSPLIT 4

using bf16x8 = __attribute__((ext_vector_type(8))) short;
using f32x4  = __attribute__((ext_vector_type(4))) float;

__device__ __forceinline__ short f2bf(float f) {
    __hip_bfloat16 h = __float2bfloat16(f);
    return *reinterpret_cast<short*>(&h);
}

// native 2^x (v_exp_f32)
__device__ __forceinline__ float exp2fast(float x) {
    return __builtin_amdgcn_exp2f(x);
}

// log2(e)/sqrt(DK): folds both the 1/sqrt(64) and the exp->exp2 conversion
#define QSCALE 0.1803368801f

// ---------------------------------------------------------------------------
// pack: blocks [0,1024): transpose+convert W{q,k,v,o} -> Wt[4096 n][1024 k] bf16
//       blocks [1024,1152): convert x -> xb bf16
// ---------------------------------------------------------------------------
__global__ __launch_bounds__(256) void pack_kernel(
    const float* __restrict__ x,
    const float* __restrict__ Wq, const float* __restrict__ Wk,
    const float* __restrict__ Wv, const float* __restrict__ Wo,
    short* __restrict__ xb, short* __restrict__ Wt) {
    const int b = blockIdx.x;
    const int t = threadIdx.x;
    if (b < 1024) {
        __shared__ short T[64][72];
        const int w = b >> 8, tile = b & 255;
        const int k0 = (tile >> 4) << 6, n0 = (tile & 15) << 6;
        const float* W = (w == 0) ? Wq : (w == 1) ? Wk : (w == 2) ? Wv : Wo;
        const int r = t >> 2, cs = (t & 3) << 4;
        #pragma unroll
        for (int u = 0; u < 4; ++u) {
            float4 v = *reinterpret_cast<const float4*>(
                &W[(size_t)(k0 + r) * NFEAT + n0 + cs + u * 4]);
            T[cs + u * 4 + 0][r] = f2bf(v.x);
            T[cs + u * 4 + 1][r] = f2bf(v.y);
            T[cs + u * 4 + 2][r] = f2bf(v.z);
            T[cs + u * 4 + 3][r] = f2bf(v.w);
        }
        __syncthreads();
        const int c = t >> 2, rs = (t & 3) << 4;
        bf16x8 a0 = *reinterpret_cast<const bf16x8*>(&T[c][rs]);
        bf16x8 a1 = *reinterpret_cast<const bf16x8*>(&T[c][rs + 8]);
        size_t drow = (size_t)(w * 1024 + n0 + c) * NFEAT + k0 + rs;
        *reinterpret_cast<bf16x8*>(&Wt[drow]) = a0;
        *reinterpret_cast<bf16x8*>(&Wt[drow + 8]) = a1;
    } else {
        const int e0 = ((b - 1024) * 256 + t) * 32;
        #pragma unroll
        for (int u = 0; u < 4; ++u) {
            float4 v0 = *reinterpret_cast<const float4*>(&x[e0 + u * 8]);
            float4 v1 = *reinterpret_cast<const float4*>(&x[e0 + u * 8 + 4]);
            bf16x8 o;
            o[0] = f2bf(v0.x); o[1] = f2bf(v0.y); o[2] = f2bf(v0.z); o[3] = f2bf(v0.w);
            o[4] = f2bf(v1.x); o[5] = f2bf(v1.y); o[6] = f2bf(v1.z); o[7] = f2bf(v1.w);
            *reinterpret_cast<bf16x8*>(&xb[e0 + u * 8]) = o;
        }
    }
}

// ---------------------------------------------------------------------------
// QKV MFMA GEMM: qkvb[1024 t][3072] = xb @ Wqkv + bias (Q cols scaled QSCALE).
// ---------------------------------------------------------------------------
__global__ __launch_bounds__(256) void qkv_gemm(
    const short* __restrict__ xb, const short* __restrict__ Wt,
    const float* __restrict__ bq, const float* __restrict__ bk,
    const float* __restrict__ bv, short* __restrict__ qkvb) {
    __shared__ short As[64][72];
    __shared__ short Bs[128][72];
    const int tid = threadIdx.x;
    const int lane = tid & 63;
    const int w = tid >> 6;
    const int l15 = lane & 15, lg = lane >> 4;
    const int wr = w >> 1, wc = w & 1;
    const int m0 = blockIdx.y << 6, n0 = blockIdx.x << 7;
    const int sel = n0 >> 10;
    const float* bias = (sel == 0) ? bq : (sel == 1) ? bk : bv;
    const float oscale = (sel == 0) ? QSCALE : 1.0f;

    f32x4 acc[2][4];
    #pragma unroll
    for (int i = 0; i < 2; ++i)
        #pragma unroll
        for (int j = 0; j < 4; ++j) acc[i][j] = (f32x4){0.f, 0.f, 0.f, 0.f};

    for (int k0 = 0; k0 < NFEAT; k0 += 64) {
        #pragma unroll
        for (int r = 0; r < 2; ++r) {
            int f = tid + (r << 8);
            int row = f >> 3, kc = (f & 7) << 3;
            *reinterpret_cast<bf16x8*>(&As[row][kc]) =
                *reinterpret_cast<const bf16x8*>(&xb[(size_t)(m0 + row) * NFEAT + k0 + kc]);
        }
        #pragma unroll
        for (int r = 0; r < 4; ++r) {
            int f = tid + (r << 8);
            int row = f >> 3, kc = (f & 7) << 3;
            *reinterpret_cast<bf16x8*>(&Bs[row][kc]) =
                *reinterpret_cast<const bf16x8*>(&Wt[(size_t)(n0 + row) * NFEAT + k0 + kc]);
        }
        __syncthreads();
        #pragma unroll
        for (int kk = 0; kk < 2; ++kk) {
            bf16x8 am[2], bn[4];
            #pragma unroll
            for (int mi = 0; mi < 2; ++mi)
                am[mi] = *reinterpret_cast<const bf16x8*>(
                    &As[wr * 32 + mi * 16 + l15][kk * 32 + lg * 8]);
            #pragma unroll
            for (int ni = 0; ni < 4; ++ni)
                bn[ni] = *reinterpret_cast<const bf16x8*>(
                    &Bs[wc * 64 + ni * 16 + l15][kk * 32 + lg * 8]);
            #pragma unroll
            for (int mi = 0; mi < 2; ++mi)
                #pragma unroll
                for (int ni = 0; ni < 4; ++ni)
                    acc[mi][ni] = __builtin_amdgcn_mfma_f32_16x16x32_bf16(
                        am[mi], bn[ni], acc[mi][ni], 0, 0, 0);
        }
        __syncthreads();
    }
    #pragma unroll
    for (int mi = 0; mi < 2; ++mi)
        #pragma unroll
        for (int rr = 0; rr < 4; ++rr) {
            int m = m0 + wr * 32 + mi * 16 + lg * 4 + rr;
            #pragma unroll
            for (int ni = 0; ni < 4; ++ni) {
                int n = n0 + wc * 64 + ni * 16 + l15;
                float v = (acc[mi][ni][rr] + bias[n & 1023]) * oscale;
                qkvb[(size_t)m * 3072 + n] = f2bf(v);
            }
        }
}

// ---------------------------------------------------------------------------
// Output MFMA GEMM: out[1024][1024] f32 = ctxb @ Wo + bo.
// ---------------------------------------------------------------------------
__global__ __launch_bounds__(256) void out_gemm(
    const short* __restrict__ ctxb, const short* __restrict__ Wt,
    const float* __restrict__ bo, float* __restrict__ out) {
    __shared__ short As[64][72];
    __shared__ short Bs[64][72];
    const int tid = threadIdx.x;
    const int lane = tid & 63;
    const int w = tid >> 6;
    const int l15 = lane & 15, lg = lane >> 4;
    const int wr = w >> 1, wc = w & 1;
    const int m0 = blockIdx.y << 6, n0 = blockIdx.x << 6;

    f32x4 acc[2][2];
    #pragma unroll
    for (int i = 0; i < 2; ++i)
        #pragma unroll
        for (int j = 0; j < 2; ++j) acc[i][j] = (f32x4){0.f, 0.f, 0.f, 0.f};

    for (int k0 = 0; k0 < NFEAT; k0 += 64) {
        #pragma unroll
        for (int r = 0; r < 2; ++r) {
            int f = tid + (r << 8);
            int row = f >> 3, kc = (f & 7) << 3;
            *reinterpret_cast<bf16x8*>(&As[row][kc]) =
                *reinterpret_cast<const bf16x8*>(&ctxb[(size_t)(m0 + row) * NFEAT + k0 + kc]);
            *reinterpret_cast<bf16x8*>(&Bs[row][kc]) =
                *reinterpret_cast<const bf16x8*>(
                    &Wt[(size_t)(3072 + n0 + row) * NFEAT + k0 + kc]);
        }
        __syncthreads();
        #pragma unroll
        for (int kk = 0; kk < 2; ++kk) {
            bf16x8 am[2], bn[2];
            #pragma unroll
            for (int mi = 0; mi < 2; ++mi)
                am[mi] = *reinterpret_cast<const bf16x8*>(
                    &As[wr * 32 + mi * 16 + l15][kk * 32 + lg * 8]);
            #pragma unroll
            for (int ni = 0; ni < 2; ++ni)
                bn[ni] = *reinterpret_cast<const bf16x8*>(
                    &Bs[wc * 32 + ni * 16 + l15][kk * 32 + lg * 8]);
            #pragma unroll
            for (int mi = 0; mi < 2; ++mi)
                #pragma unroll
                for (int ni = 0; ni < 2; ++ni)
                    acc[mi][ni] = __builtin_amdgcn_mfma_f32_16x16x32_bf16(
                        am[mi], bn[ni], acc[mi][ni], 0, 0, 0);
        }
        __syncthreads();
    }
    #pragma unroll
    for (int mi = 0; mi < 2; ++mi)
        #pragma unroll
        for (int rr = 0; rr < 4; ++rr) {
            int m = m0 + wr * 32 + mi * 16 + lg * 4 + rr;
            #pragma unroll
            for (int ni = 0; ni < 2; ++ni) {
                int n = n0 + wc * 32 + ni * 16 + l15;
                out[(size_t)m * NFEAT + n] = acc[mi][ni][rr] + bo[n];
            }
        }
}

// ---------------------------------------------------------------------------
// gather: kg[16 h][4096 tok][64 d] bf16 and vt[16 h][64 d][4096 tok] bf16.
// ---------------------------------------------------------------------------
__global__ __launch_bounds__(256) void gather_kv(
    const float* __restrict__ kc, const float* __restrict__ vc,
    const short* __restrict__ qkvb, const int* __restrict__ btab,
    const int* __restrict__ soff, short* __restrict__ kg, short* __restrict__ vt) {
    __shared__ short TV[64][72];
    const int h = blockIdx.x;
    const int t0 = blockIdx.y << 6;
    const int offset = soff[0], total = offset + TCHUNK;
    const int t = threadIdx.x;
    const int row = t >> 2, ds = (t & 3) << 4;
    const int tok = t0 + row;
    short kv[16], vv[16];
    if (tok < offset) {
        int phys = btab[tok >> 5];
        size_t base = ((size_t)(phys * 32 + (tok & 31)) * NHEAD + h) * DK + ds;
        #pragma unroll
        for (int u = 0; u < 4; ++u) {
            float4 kf = *reinterpret_cast<const float4*>(&kc[base + u * 4]);
            float4 vf = *reinterpret_cast<const float4*>(&vc[base + u * 4]);
            kv[u * 4 + 0] = f2bf(kf.x); kv[u * 4 + 1] = f2bf(kf.y);
            kv[u * 4 + 2] = f2bf(kf.z); kv[u * 4 + 3] = f2bf(kf.w);
            vv[u * 4 + 0] = f2bf(vf.x); vv[u * 4 + 1] = f2bf(vf.y);
            vv[u * 4 + 2] = f2bf(vf.z); vv[u * 4 + 3] = f2bf(vf.w);
        }
    } else if (tok < total) {
        size_t base = (size_t)(tok - offset) * 3072 + 1024 + h * DK + ds;
        bf16x8 k0 = *reinterpret_cast<const bf16x8*>(&qkvb[base]);
        bf16x8 k1 = *reinterpret_cast<const bf16x8*>(&qkvb[base + 8]);
        bf16x8 v0 = *reinterpret_cast<const bf16x8*>(&qkvb[base + 1024]);
        bf16x8 v1 = *reinterpret_cast<const bf16x8*>(&qkvb[base + 1032]);
        #pragma unroll
        for (int e = 0; e < 8; ++e) {
            kv[e] = k0[e]; kv[8 + e] = k1[e];
            vv[e] = v0[e]; vv[8 + e] = v1[e];
        }
    } else {
        #pragma unroll
        for (int e = 0; e < 16; ++e) { kv[e] = 0; vv[e] = 0; }
    }
    {
        bf16x8 a, b;
        #pragma unroll
        for (int e = 0; e < 8; ++e) { a[e] = kv[e]; b[e] = kv[8 + e]; }
        size_t kb = ((size_t)h * MAXTOK + tok) * DK + ds;
        *reinterpret_cast<bf16x8*>(&kg[kb]) = a;
        *reinterpret_cast<bf16x8*>(&kg[kb + 8]) = b;
    }
    #pragma unroll
    for (int e = 0; e < 16; ++e) TV[ds + e][row] = vv[e];
    __syncthreads();
    {
        const int d = t >> 2, ts = (t & 3) << 4;
        bf16x8 a = *reinterpret_cast<const bf16x8*>(&TV[d][ts]);
        bf16x8 b = *reinterpret_cast<const bf16x8*>(&TV[d][ts + 8]);
        size_t vb = ((size_t)h * DK + d) * MAXTOK + t0 + ts;
        *reinterpret_cast<bf16x8*>(&vt[vb]) = a;
        *reinterpret_cast<bf16x8*>(&vt[vb + 8]) = b;
    }
}

// ---------------------------------------------------------------------------
// MFMA flash attention v5. Grid (16 h, 16 qt, NSPLIT z), block 256 (4 waves).
// No phase split: all 4 waves consume the same staged K/V tile; each wave owns
// 16 q-rows. Register-prefetch next tile (T14). Defer-max (T13): per-tile
// in-lane max + __all ballot; butterfly+rescale only when max grows. Row-sum
// of P via MFMA with all-ones B (no sum butterflies). exp2 domain (QSCALE
// includes log2e). Partials (unnormalized acc + m/l per q) to pacc; merged
// by merge_ctx. All blocks of head h land on XCD h%8 (16*16 grid, 16%8==0).
// ---------------------------------------------------------------------------
__global__ __launch_bounds__(256, 4) void attn_mfma(
    const short* __restrict__ qkvb, const short* __restrict__ kg,
    const short* __restrict__ vt, const int* __restrict__ soff,
    float* __restrict__ pacc) {
    __shared__ short Ks[64][72];
    __shared__ short Vs[64][72];   // [d][tok]
    __shared__ short Ps[4][16][72];

    const int tid = threadIdx.x;
    const int lane = tid & 63;
    const int w = tid >> 6;
    const int l15 = lane & 15;
    const int lg = lane >> 4;
    const int h = blockIdx.x;
    const int qt = blockIdx.y;
    const int z = blockIdx.z;
    const int offset = soff[0];
    const int total = offset + TCHUNK;
    const int ntiles = (total + 63) >> 6;
    const int NT = (ntiles + NSPLIT - 1) / NSPLIT;
    const int tbase = z * NT;
    const int tend = min(tbase + NT, ntiles);

    const int srow = tid >> 2;            // staging row (tok for K, d for V)
    const int sds = (tid & 3) << 4;       // staging 16-elem segment

    const short* kbase = kg + (size_t)h * MAXTOK * DK;
    const short* vbase = vt + (size_t)h * DK * MAXTOK;

    // Q A-fragments (q = qt*64 + w*16 + l15, pre-scaled by QSCALE upstream)
    const size_t qrow = (size_t)(qt * 64 + w * 16 + l15) * 3072 + h * DK;
    bf16x8 aq0 = *reinterpret_cast<const bf16x8*>(&qkvb[qrow + lg * 8]);
    bf16x8 aq1 = *reinterpret_cast<const bf16x8*>(&qkvb[qrow + 32 + lg * 8]);

    bf16x8 ones;
    #pragma unroll
    for (int e = 0; e < 8; ++e) ones[e] = (short)0x3F80;   // bf16 1.0

    float m[4];
    f32x4 acc[4], acc1;
    #pragma unroll
    for (int r = 0; r < 4; ++r) m[r] = -1e30f;
    #pragma unroll
    for (int fc = 0; fc < 4; ++fc) acc[fc] = (f32x4){0.f, 0.f, 0.f, 0.f};
    acc1 = (f32x4){0.f, 0.f, 0.f, 0.f};

    bf16x8 kr0, kr1, vr0, vr1;
    if (tbase < tend) {
        int tok0 = tbase << 6;
        size_t kb = (size_t)(tok0 + srow) * DK + sds;
        kr0 = *reinterpret_cast<const bf16x8*>(&kbase[kb]);
        kr1 = *reinterpret_cast<const bf16x8*>(&kbase[kb + 8]);
        size_t vb = (size_t)srow * MAXTOK + tok0 + sds;
        vr0 = *reinterpret_cast<const bf16x8*>(&vbase[vb]);
        vr1 = *reinterpret_cast<const bf16x8*>(&vbase[vb + 8]);
    }

    for (int t = tbase; t < tend; ++t) {
        __syncthreads();   // previous tile fully consumed
        *reinterpret_cast<bf16x8*>(&Ks[srow][sds]) = kr0;
        *reinterpret_cast<bf16x8*>(&Ks[srow][sds + 8]) = kr1;
        *reinterpret_cast<bf16x8*>(&Vs[srow][sds]) = vr0;
        *reinterpret_cast<bf16x8*>(&Vs[srow][sds + 8]) = vr1;
        __syncthreads();   // staged tile visible
        if (t + 1 < tend) {   // prefetch next tile into regs (hides L2 latency)
            int tok0 = (t + 1) << 6;
            size_t kb = (size_t)(tok0 + srow) * DK + sds;
            kr0 = *reinterpret_cast<const bf16x8*>(&kbase[kb]);
            kr1 = *reinterpret_cast<const bf16x8*>(&kbase[kb + 8]);
            size_t vb = (size_t)srow * MAXTOK + tok0 + sds;
            vr0 = *reinterpret_cast<const bf16x8*>(&vbase[vb]);
            vr1 = *reinterpret_cast<const bf16x8*>(&vbase[vb + 8]);
        }

        const int kt0 = t << 6;
        // ---- QK^T ----
        bf16x8 kb0[4], kb1[4];
        #pragma unroll
        for (int fc = 0; fc < 4; ++fc) {
            kb0[fc] = *reinterpret_cast<const bf16x8*>(&Ks[fc * 16 + l15][lg * 8]);
            kb1[fc] = *reinterpret_cast<const bf16x8*>(&Ks[fc * 16 + l15][32 + lg * 8]);
        }
        f32x4 s[4];
        __builtin_amdgcn_s_setprio(1);
        #pragma unroll
        for (int fc = 0; fc < 4; ++fc) {
            s[fc] = __builtin_amdgcn_mfma_f32_16x16x32_bf16(
                aq0, kb0[fc], (f32x4){0.f, 0.f, 0.f, 0.f}, 0, 0, 0);
            s[fc] = __builtin_amdgcn_mfma_f32_16x16x32_bf16(
                aq1, kb1[fc], s[fc], 0, 0, 0);
        }
        __builtin_amdgcn_s_setprio(0);
        if (kt0 + 64 > total) {   // uniform branch; only possible last tile
            #pragma unroll
            for (int fc = 0; fc < 4; ++fc) {
                bool valid = (kt0 + fc * 16 + l15) < total;
                #pragma unroll
                for (int r = 0; r < 4; ++r)
                    s[fc][r] = valid ? s[fc][r] : -1e30f;
            }
        }
        // ---- defer-max online softmax ----
        float lm[4];
        #pragma unroll
        for (int r = 0; r < 4; ++r)
            lm[r] = fmaxf(fmaxf(s[0][r], s[1][r]), fmaxf(s[2][r], s[3][r]));
        bool ok = lm[0] <= m[0] + 8.f && lm[1] <= m[1] + 8.f &&
                  lm[2] <= m[2] + 8.f && lm[3] <= m[3] + 8.f;
        if (!__all(ok)) {
            #pragma unroll
            for (int r = 0; r < 4; ++r) {
                float tm = lm[r];
                tm = fmaxf(tm, __shfl_xor(tm, 1));
                tm = fmaxf(tm, __shfl_xor(tm, 2));
                tm = fmaxf(tm, __shfl_xor(tm, 4));
                tm = fmaxf(tm, __shfl_xor(tm, 8));
                float mn = fmaxf(m[r], tm);
                float sc = exp2fast(m[r] - mn);
                m[r] = mn;
                acc1[r] *= sc;
                #pragma unroll
                for (int fc = 0; fc < 4; ++fc) acc[fc][r] *= sc;
            }
        }
        // ---- P = exp2(s - m), write to per-wave LDS in A-frag layout ----
        #pragma unroll
        for (int fc = 0; fc < 4; ++fc)
            #pragma unroll
            for (int r = 0; r < 4; ++r)
                Ps[w][lg * 4 + r][l15 + 16 * fc] = f2bf(exp2fast(s[fc][r] - m[r]));
        // ---- PV (+ row-sum via ones-MFMA) ----
        #pragma unroll
        for (int ks = 0; ks < 2; ++ks) {
            bf16x8 pa = *reinterpret_cast<const bf16x8*>(
                &Ps[w][l15][ks * 32 + lg * 8]);
            __builtin_amdgcn_s_setprio(1);
            acc1 = __builtin_amdgcn_mfma_f32_16x16x32_bf16(pa, ones, acc1, 0, 0, 0);
            #pragma unroll
            for (int fc = 0; fc < 4; ++fc) {
                bf16x8 bv = *reinterpret_cast<const bf16x8*>(
                    &Vs[fc * 16 + l15][ks * 32 + lg * 8]);
                acc[fc] = __builtin_amdgcn_mfma_f32_16x16x32_bf16(pa, bv, acc[fc], 0, 0, 0);
            }
            __builtin_amdgcn_s_setprio(0);
        }
    }

    // ---- write this split's partial (unnormalized) ----
    const size_t pbase = (((size_t)z * NHEAD + h) * 16 + qt) * 4224;
    #pragma unroll
    for (int r = 0; r < 4; ++r) {
        int q = w * 16 + lg * 4 + r;
        if (l15 == 0) {
            pacc[pbase + 4096 + q] = m[r];
            pacc[pbase + 4160 + q] = acc1[r];
        }
        #pragma unroll
        for (int fc = 0; fc < 4; ++fc)
            pacc[pbase + q * 64 + l15 + 16 * fc] = acc[fc][r];
    }
}

// ---------------------------------------------------------------------------
// merge NSPLIT split partials -> ctxb bf16 [1024 t][1024 (h*64+d)]
// ---------------------------------------------------------------------------
__global__ __launch_bounds__(256) void merge_ctx(
    const float* __restrict__ pacc, short* __restrict__ ctxb) {
    const int h = blockIdx.x, qt = blockIdx.y;
    const int t = threadIdx.x;
    const int q = t >> 2, ds = (t & 3) << 4;
    size_t b[NSPLIT];
    float mz[NSPLIT], lz[NSPLIT];
    float M = -1e30f;
    #pragma unroll
    for (int z = 0; z < NSPLIT; ++z) {
        b[z] = (((size_t)z * NHEAD + h) * 16 + qt) * 4224;
        mz[z] = pacc[b[z] + 4096 + q];
        lz[z] = pacc[b[z] + 4160 + q];
        M = fmaxf(M, mz[z]);
    }
    float L = 0.f, ez[NSPLIT];
    #pragma unroll
    for (int z = 0; z < NSPLIT; ++z) {
        ez[z] = __builtin_amdgcn_exp2f(mz[z] - M);
        L += lz[z] * ez[z];
    }
    float inv = 1.f / L;
    bf16x8 o0, o1;
    #pragma unroll
    for (int j = 0; j < 8; ++j) {
        float v = 0.f;
        #pragma unroll
        for (int z = 0; z < NSPLIT; ++z)
            v += pacc[b[z] + q * 64 + ds + j] * ez[z];
        o0[j] = f2bf(v * inv);
    }
    #pragma unroll
    for (int j = 0; j < 8; ++j) {
        float v = 0.f;
        #pragma unroll
        for (int z = 0; z < NSPLIT; ++z)
            v += pacc[b[z] + q * 64 + ds + 8 + j] * ez[z];
        o1[j] = f2bf(v * inv);
    }
    size_t ob = (size_t)(qt * 64 + q) * NFEAT + h * DK + ds;
    *reinterpret_cast<bf16x8*>(&ctxb[ob]) = o0;
    *reinterpret_cast<bf16x8*>(&ctxb[ob + 8]) = o1;
}

extern "C" void kernel_launch(void* const* d_in, const int* in_sizes, int n_in,
                              void* d_out, int out_size, void* d_ws, size_t ws_size,
                              hipStream_t stream) {
    const float* x   = (const float*)d_in[0];
    const float* Wq  = (const float*)d_in[1];
    const float* bq  = (const float*)d_in[2];
    const float* Wk  = (const float*)d_in[3];
    const float* bk  = (const float*)d_in[4];
    const float* Wv  = (const float*)d_in[5];
    const float* bv  = (const float*)d_in[6];
    const float* Wo  = (const float*)d_in[7];
    const float* bo  = (const float*)d_in[8];
    const float* kc  = (const float*)d_in[9];
    const float* vc  = (const float*)d_in[10];
    const int*   bt  = (const int*)d_in[11];
    const int*   so  = (const int*)d_in[12];

    short* xb   = (short*)d_ws;                       // 1M bf16
    short* Wt   = xb + (size_t)1024 * 1024;           // 4M bf16
    short* qkvb = Wt + (size_t)4096 * 1024;           // 3M bf16
    short* kg   = qkvb + (size_t)1024 * 3072;         // 4M bf16
    short* vtb  = kg + (size_t)NHEAD * MAXTOK * DK;   // 4M bf16
    float* pacc = (float*)(vtb + (size_t)NHEAD * DK * MAXTOK);  // NSPLIT*256*4224 f32
    short* ctxb = (short*)(pacc + (size_t)NSPLIT * 256 * 4224); // 1M bf16

    pack_kernel<<<dim3(1152), 256, 0, stream>>>(x, Wq, Wk, Wv, Wo, xb, Wt);
    qkv_gemm<<<dim3(24, 16), 256, 0, stream>>>(xb, Wt, bq, bk, bv, qkvb);
    gather_kv<<<dim3(16, 64), 256, 0, stream>>>(kc, vc, qkvb, bt, so, kg, vtb);
    attn_mfma<<<dim3(16, 16, NSPLIT), 256, 0, stream>>>(qkvb, kg, vtb, so, pacc);
    merge_ctx<<<dim3(16, 16), 256, 0, stream>>>(pacc, ctxb);
    out_gemm<<<dim3(16, 16), 256, 0, stream>>>(ctxb, Wt, bo, (float*)d_out);
}